// Round 1
// baseline (313.501 us; speedup 1.0000x reference)
//
#include <hip/hip_runtime.h>
#include <math.h>

namespace {

constexpr int PN = 131072;
constexpr int SN = 64;
constexpr int EH = 512;
constexpr int EW = 1024;
constexpr float FPI = 3.14159265358979323846f;
constexpr float INV_PI = 0.31830988618379067154f;

struct F3 { float x, y, z; };

__device__ __forceinline__ float dot3(F3 a, F3 b) { return a.x*b.x + a.y*b.y + a.z*b.z; }
__device__ __forceinline__ F3 cross3(F3 a, F3 b) {
    return F3{a.y*b.z - a.z*b.y, a.z*b.x - a.x*b.z, a.x*b.y - a.y*b.x};
}
__device__ __forceinline__ F3 norm3(F3 a) {
    float l = sqrtf(a.x*a.x + a.y*a.y + a.z*a.z);
    float inv = 1.0f / fmaxf(l, 1e-12f);
    return F3{a.x*inv, a.y*inv, a.z*inv};
}
__device__ __forceinline__ float clampf(float x, float lo, float hi) {
    return fminf(fmaxf(x, lo), hi);
}
__device__ __forceinline__ float smithf(float alpha, float c) {
    float a2 = alpha*alpha;
    return 2.0f*c / (c + sqrtf(a2 + (1.0f - a2)*c*c));
}

// bilinear lat-long env lookup with border clamp, matching _grid_sample_border
template<bool TEX>
__device__ __forceinline__ F3 sample_env(const float* __restrict__ img,
                                         const float4* __restrict__ tex,
                                         F3 d) {
    float uu = 0.5f*(1.0f + atan2f(d.x, -d.z)*INV_PI);
    float vv = acosf(clampf(d.y, -1.0f, 1.0f))*INV_PI;
    float gx = uu*2.0f - 1.0f;
    float gy = vv*2.0f - 1.0f;
    float x = ((gx + 1.0f)*(float)EW - 1.0f)*0.5f;
    float y = ((gy + 1.0f)*(float)EH - 1.0f)*0.5f;
    float x0f = floorf(x), y0f = floorf(y);
    float wx = x - x0f, wy = y - y0f;
    int ix = (int)x0f, iy = (int)y0f;
    int x0 = min(max(ix, 0), EW - 1);
    int x1 = min(max(ix + 1, 0), EW - 1);
    int y0 = min(max(iy, 0), EH - 1);
    int y1 = min(max(iy + 1, 0), EH - 1);
    float w00 = (1.0f - wx)*(1.0f - wy);
    float w01 = wx*(1.0f - wy);
    float w10 = (1.0f - wx)*wy;
    float w11 = wx*wy;
    if (TEX) {
        float4 v00 = tex[y0*EW + x0];
        float4 v01 = tex[y0*EW + x1];
        float4 v10 = tex[y1*EW + x0];
        float4 v11 = tex[y1*EW + x1];
        return F3{v00.x*w00 + v01.x*w01 + v10.x*w10 + v11.x*w11,
                  v00.y*w00 + v01.y*w01 + v10.y*w10 + v11.y*w11,
                  v00.z*w00 + v01.z*w01 + v10.z*w10 + v11.z*w11};
    } else {
        const int HW = EH*EW;
        float o0, o1, o2;
        {
            const float* pl = img;
            o0 = pl[y0*EW + x0]*w00 + pl[y0*EW + x1]*w01 + pl[y1*EW + x0]*w10 + pl[y1*EW + x1]*w11;
        }
        {
            const float* pl = img + HW;
            o1 = pl[y0*EW + x0]*w00 + pl[y0*EW + x1]*w01 + pl[y1*EW + x0]*w10 + pl[y1*EW + x1]*w11;
        }
        {
            const float* pl = img + 2*HW;
            o2 = pl[y0*EW + x0]*w00 + pl[y0*EW + x1]*w01 + pl[y1*EW + x0]*w10 + pl[y1*EW + x1]*w11;
        }
        return F3{o0, o1, o2};
    }
}

__device__ __forceinline__ float wave_sum(float x) {
    #pragma unroll
    for (int m = 32; m >= 1; m >>= 1) x += __shfl_xor(x, m, 64);
    return x;
}

__global__ void relayout_kernel(const float* __restrict__ img, float4* __restrict__ tex) {
    int i = blockIdx.x*blockDim.x + threadIdx.x;
    const int HW = EH*EW;
    if (i < HW) {
        tex[i] = make_float4(img[i], img[HW + i], img[2*HW + i], 0.0f);
    }
}

template<bool TEX>
__global__ __launch_bounds__(256) void ibl_kernel(
    const float* __restrict__ emap, const float4* __restrict__ tex,
    const float* __restrict__ view_dir, const float* __restrict__ normal,
    const float* __restrict__ albedo, const float* __restrict__ rough_,
    const float* __restrict__ metal_, const float* __restrict__ u1_,
    const float* __restrict__ u2_, const float* __restrict__ uc_,
    const float* __restrict__ vc_, float* __restrict__ out)
{
    int gtid = blockIdx.x*blockDim.x + threadIdx.x;
    int p = gtid >> 6;            // one wave per point
    int lane = threadIdx.x & 63;  // one lane per sample
    if (p >= PN) return;

    // ---- per-point (lane-uniform) ----
    F3 v   = F3{view_dir[3*p], view_dir[3*p+1], view_dir[3*p+2]};
    F3 n   = F3{normal[3*p],   normal[3*p+1],   normal[3*p+2]};
    F3 alb = F3{albedo[3*p],   albedo[3*p+1],   albedo[3*p+2]};
    float rough = rough_[p];
    float alpha = rough*rough;
    float metal = metal_[p];

    // TBN (rows: tangent, bitangent, normal)
    F3 t;
    float nx2nz2 = n.x*n.x + n.z*n.z;
    if (nx2nz2 <= 0.0f) t = F3{1.0f, 0.0f, 0.0f};
    else                t = norm3(F3{n.z, 0.0f, -n.x});
    F3 b = norm3(cross3(n, t));

    F3 vl = F3{dot3(t, v), dot3(b, v), dot3(n, v)};  // v_local

    float ndv = clampf(dot3(n, v), 0.0f, 1.0f);
    float s_ndv = smithf(alpha, ndv);
    float smith_view = clampf(s_ndv, 1e-10f, 1.0f);
    float inv_sv = 1.0f / smith_view;

    F3 f0 = F3{metal*alb.x + (1.0f - metal)*0.04f,
               metal*alb.y + (1.0f - metal)*0.04f,
               metal*alb.z + (1.0f - metal)*0.04f};
    F3 kd = F3{alb.x*(1.0f - metal), alb.y*(1.0f - metal), alb.z*(1.0f - metal)};

    // VNDF frame (per-point in reference)
    F3 vh = norm3(F3{vl.x*alpha, vl.y*alpha, vl.z});
    F3 b1;
    float l2d = sqrtf(vh.x*vh.x + vh.y*vh.y);
    if (l2d <= 0.0f) b1 = F3{1.0f, 0.0f, 0.0f};
    else             b1 = norm3(F3{-vh.y, vh.x, 0.0f});
    F3 b2 = norm3(cross3(vh, b1));
    float sfac = 0.5f*(1.0f + vh.z);

    // ---- per-sample (one per lane) ----
    size_t si = (size_t)p*SN + lane;
    float U1 = u1_[si], U2 = u2_[si], UC = uc_[si], VC = vc_[si];

    // GGX VNDF sample
    float r = sqrtf(U1);
    float theta = 2.0f*FPI*U2;
    float sth, cth;
    sincosf(theta, &sth, &cth);
    float t1 = r*cth;
    float t2 = r*sth;
    t2 = (1.0f - sfac)*sqrtf(fmaxf(1.0f - t1*t1, 0.0f)) + sfac*t2;
    float t3 = sqrtf(clampf(1.0f - t1*t1 - t2*t2, 0.0f, 1.0f));
    F3 mh = F3{t1*b1.x + t2*b2.x + t3*vh.x,
               t1*b1.y + t2*b2.y + t3*vh.y,
               t1*b1.z + t2*b2.z + t3*vh.z};
    F3 ml = norm3(F3{mh.x*alpha, mh.y*alpha, mh.z});
    // local -> world
    F3 m = F3{t.x*ml.x + b.x*ml.y + n.x*ml.z,
              t.y*ml.x + b.y*ml.y + n.y*ml.z,
              t.z*ml.x + b.z*ml.y + n.z*ml.z};
    // reflect view about m
    float idm = dot3(v, m);
    F3 light = norm3(F3{-v.x + 2.0f*idm*m.x,
                        -v.y + 2.0f*idm*m.y,
                        -v.z + 2.0f*idm*m.z});

    F3 rad = sample_env<TEX>(emap, tex, light);

    F3 hlf = norm3(F3{v.x + light.x, v.y + light.y, v.z + light.z});
    float hdv = clampf(dot3(hlf, v), 0.0f, 1.0f);
    float ndl = clampf(dot3(n, light), 0.0f, 1.0f);
    float s_ndl = smithf(alpha, ndl);
    float geom = s_ndv*s_ndl;
    float om = 1.0f - hdv;
    float om2 = om*om;
    float om5 = om2*om2*om;
    float gs = geom*inv_sv;

    F3 acc;
    acc.x = (f0.x + (1.0f - f0.x)*om5)*gs*rad.x;
    acc.y = (f0.y + (1.0f - f0.y)*om5)*gs*rad.y;
    acc.z = (f0.z + (1.0f - f0.z)*om5)*gs*rad.z;

    // cosine-hemisphere diffuse sample
    float phi = 2.0f*FPI*UC;
    float sph, cph;
    sincosf(phi, &sph, &cph);
    float ct = sqrtf(VC);
    float st = sqrtf(fmaxf(1.0f - VC, 0.0f));
    F3 ldl = F3{cph*st, sph*st, ct};
    F3 ld = F3{t.x*ldl.x + b.x*ldl.y + n.x*ldl.z,
               t.y*ldl.x + b.y*ldl.y + n.y*ldl.z,
               t.z*ldl.x + b.z*ldl.y + n.z*ldl.z};
    F3 radd = sample_env<TEX>(emap, tex, ld);

    acc.x += radd.x*kd.x;
    acc.y += radd.y*kd.y;
    acc.z += radd.z*kd.z;

    // mean over S via wave butterfly reduce
    acc.x = wave_sum(acc.x);
    acc.y = wave_sum(acc.y);
    acc.z = wave_sum(acc.z);

    if (lane == 0) {
        const float inv_s = 1.0f/(float)SN;
        out[3*p + 0] = acc.x*inv_s;
        out[3*p + 1] = acc.y*inv_s;
        out[3*p + 2] = acc.z*inv_s;
    }
}

} // anonymous namespace

extern "C" void kernel_launch(void* const* d_in, const int* in_sizes, int n_in,
                              void* d_out, int out_size, void* d_ws, size_t ws_size,
                              hipStream_t stream) {
    const float* emap     = (const float*)d_in[0];
    const float* view_dir = (const float*)d_in[1];
    const float* normal   = (const float*)d_in[2];
    const float* albedo   = (const float*)d_in[3];
    const float* rough    = (const float*)d_in[4];
    const float* metal    = (const float*)d_in[5];
    const float* u1       = (const float*)d_in[6];
    const float* u2       = (const float*)d_in[7];
    const float* uc       = (const float*)d_in[8];
    const float* vc       = (const float*)d_in[9];
    float* out            = (float*)d_out;

    const int HW = EH*EW;
    const size_t tex_bytes = (size_t)HW*sizeof(float4);
    const int main_blocks = PN*SN/256;  // one wave (64 lanes) per point, 4 points/block

    if (ws_size >= tex_bytes) {
        float4* tex = (float4*)d_ws;
        relayout_kernel<<<(HW + 255)/256, 256, 0, stream>>>(emap, tex);
        ibl_kernel<true><<<main_blocks, 256, 0, stream>>>(
            emap, tex, view_dir, normal, albedo, rough, metal, u1, u2, uc, vc, out);
    } else {
        ibl_kernel<false><<<main_blocks, 256, 0, stream>>>(
            emap, nullptr, view_dir, normal, albedo, rough, metal, u1, u2, uc, vc, out);
    }
}

// Round 2
// 230.264 us; speedup vs baseline: 1.3615x; 1.3615x over previous
//
#include <hip/hip_runtime.h>
#include <hip/hip_fp16.h>
#include <math.h>

namespace {

constexpr int PN = 131072;
constexpr int SN = 64;
constexpr int EH = 512;
constexpr int EW = 1024;
constexpr float FPI = 3.14159265358979323846f;

struct F3 { float x, y, z; };

struct alignas(8) H4 { __half2 rg; __half2 ba; };

__device__ __forceinline__ float dot3(F3 a, F3 b) { return a.x*b.x + a.y*b.y + a.z*b.z; }
__device__ __forceinline__ F3 cross3(F3 a, F3 b) {
    return F3{a.y*b.z - a.z*b.y, a.z*b.x - a.x*b.z, a.x*b.y - a.y*b.x};
}
__device__ __forceinline__ float clampf(float x, float lo, float hi) {
    return fminf(fmaxf(x, lo), hi);
}
// normalize via hardware rsqrt (1-ulp); matches x / max(||x||, 1e-12) semantics
__device__ __forceinline__ F3 norm3(F3 a) {
    float l2 = a.x*a.x + a.y*a.y + a.z*a.z;
    float inv = __builtin_amdgcn_rsqf(fmaxf(l2, 1e-24f));
    return F3{a.x*inv, a.y*inv, a.z*inv};
}
__device__ __forceinline__ float smithf(float alpha, float c) {
    float a2 = alpha*alpha;
    float den = c + __builtin_amdgcn_sqrtf(a2 + (1.0f - a2)*c*c);
    return 2.0f*c*__builtin_amdgcn_rcpf(den);
}

// atan2 via degree-11 odd minimax (abs err ~1e-6 rad; budget 6e-5 rad)
__device__ __forceinline__ float fast_atan2(float y, float x) {
    float ax = fabsf(x), ay = fabsf(y);
    float mx = fmaxf(ax, ay), mn = fminf(ax, ay);
    float a = mn * __builtin_amdgcn_rcpf(mx);
    if (mx == 0.0f) a = 0.0f;          // atan2(0,0) -> 0
    float s = a*a;
    float p = fmaf(s, -0.01172120f, 0.05265332f);
    p = fmaf(s, p, -0.11643287f);
    p = fmaf(s, p,  0.19354346f);
    p = fmaf(s, p, -0.33262347f);
    p = fmaf(s, p,  0.99997726f);
    float r = p * a;
    if (ay > ax)  r = 1.57079632679f - r;
    if (x < 0.0f) r = 3.14159265359f - r;
    return copysignf(r, y);
}

// acos via A&S 4.4.46 sqrt*poly (abs err ~1e-6 rad); x pre-clamped to [-1,1]
__device__ __forceinline__ float fast_acos(float x) {
    float ax = fabsf(x);
    float p = fmaf(ax, -0.0012624911f, 0.0066700901f);
    p = fmaf(ax, p, -0.0170881256f);
    p = fmaf(ax, p,  0.0308918810f);
    p = fmaf(ax, p, -0.0501743046f);
    p = fmaf(ax, p,  0.0889789874f);
    p = fmaf(ax, p, -0.2145988016f);
    p = fmaf(ax, p,  1.5707963050f);
    float s = __builtin_amdgcn_sqrtf(fmaxf(1.0f - ax, 0.0f));
    float r = s * p;
    return (x >= 0.0f) ? r : 3.14159265359f - r;
}

// bilinear lat-long env lookup with border clamp, matching _grid_sample_border
template<bool TEX>
__device__ __forceinline__ F3 sample_env(const float* __restrict__ img,
                                         const H4* __restrict__ tex,
                                         F3 d) {
    float t  = fast_atan2(d.x, -d.z);
    float vv = fast_acos(clampf(d.y, -1.0f, 1.0f));
    // x = u*W - 0.5 = 512 + t*(512/pi) - 0.5 ; y = v*H - 0.5 = acos*(512/pi) - 0.5
    const float SPI = 512.0f / FPI;
    float x = fmaf(t,  SPI, 511.5f);
    float y = fmaf(vv, SPI, -0.5f);
    float x0f = floorf(x), y0f = floorf(y);
    float wx = x - x0f, wy = y - y0f;
    int ix = (int)x0f, iy = (int)y0f;
    int x0 = min(max(ix, 0), EW - 1);
    int x1 = min(max(ix + 1, 0), EW - 1);
    int y0 = min(max(iy, 0), EH - 1);
    int y1 = min(max(iy + 1, 0), EH - 1);
    float w00 = (1.0f - wx)*(1.0f - wy);
    float w01 = wx*(1.0f - wy);
    float w10 = (1.0f - wx)*wy;
    float w11 = wx*wy;
    if (TEX) {
        H4 t00 = tex[y0*EW + x0];
        H4 t01 = tex[y0*EW + x1];
        H4 t10 = tex[y1*EW + x0];
        H4 t11 = tex[y1*EW + x1];
        float2 rg00 = __half22float2(t00.rg);
        float2 rg01 = __half22float2(t01.rg);
        float2 rg10 = __half22float2(t10.rg);
        float2 rg11 = __half22float2(t11.rg);
        float b00 = __half2float(__low2half(t00.ba));
        float b01 = __half2float(__low2half(t01.ba));
        float b10 = __half2float(__low2half(t10.ba));
        float b11 = __half2float(__low2half(t11.ba));
        return F3{rg00.x*w00 + rg01.x*w01 + rg10.x*w10 + rg11.x*w11,
                  rg00.y*w00 + rg01.y*w01 + rg10.y*w10 + rg11.y*w11,
                  b00*w00 + b01*w01 + b10*w10 + b11*w11};
    } else {
        const int HW = EH*EW;
        float o0, o1, o2;
        {
            const float* pl = img;
            o0 = pl[y0*EW + x0]*w00 + pl[y0*EW + x1]*w01 + pl[y1*EW + x0]*w10 + pl[y1*EW + x1]*w11;
        }
        {
            const float* pl = img + HW;
            o1 = pl[y0*EW + x0]*w00 + pl[y0*EW + x1]*w01 + pl[y1*EW + x0]*w10 + pl[y1*EW + x1]*w11;
        }
        {
            const float* pl = img + 2*HW;
            o2 = pl[y0*EW + x0]*w00 + pl[y0*EW + x1]*w01 + pl[y1*EW + x0]*w10 + pl[y1*EW + x1]*w11;
        }
        return F3{o0, o1, o2};
    }
}

__device__ __forceinline__ float wave_sum(float x) {
    #pragma unroll
    for (int m = 32; m >= 1; m >>= 1) x += __shfl_xor(x, m, 64);
    return x;
}

__global__ void relayout_kernel(const float* __restrict__ img, H4* __restrict__ tex) {
    int i = blockIdx.x*blockDim.x + threadIdx.x;
    const int HW = EH*EW;
    if (i < HW) {
        H4 h;
        h.rg = __floats2half2_rn(img[i], img[HW + i]);
        h.ba = __floats2half2_rn(img[2*HW + i], 0.0f);
        tex[i] = h;
    }
}

template<bool TEX>
__global__ __launch_bounds__(256) void ibl_kernel(
    const float* __restrict__ emap, const H4* __restrict__ tex,
    const float* __restrict__ view_dir, const float* __restrict__ normal,
    const float* __restrict__ albedo, const float* __restrict__ rough_,
    const float* __restrict__ metal_, const float* __restrict__ u1_,
    const float* __restrict__ u2_, const float* __restrict__ uc_,
    const float* __restrict__ vc_, float* __restrict__ out)
{
    int gtid = blockIdx.x*blockDim.x + threadIdx.x;
    int p = gtid >> 6;            // one wave per point
    int lane = threadIdx.x & 63;  // one lane per sample
    if (p >= PN) return;

    // ---- per-point (lane-uniform) ----
    F3 v   = F3{view_dir[3*p], view_dir[3*p+1], view_dir[3*p+2]};
    F3 n   = F3{normal[3*p],   normal[3*p+1],   normal[3*p+2]};
    F3 alb = F3{albedo[3*p],   albedo[3*p+1],   albedo[3*p+2]};
    float rough = rough_[p];
    float alpha = rough*rough;
    float metal = metal_[p];

    // TBN (rows: tangent, bitangent, normal)
    F3 t;
    float nx2nz2 = n.x*n.x + n.z*n.z;
    if (nx2nz2 <= 0.0f) t = F3{1.0f, 0.0f, 0.0f};
    else                t = norm3(F3{n.z, 0.0f, -n.x});
    F3 b = norm3(cross3(n, t));

    F3 vl = F3{dot3(t, v), dot3(b, v), dot3(n, v)};  // v_local

    float ndv = clampf(dot3(n, v), 0.0f, 1.0f);
    float s_ndv = smithf(alpha, ndv);
    float smith_view = clampf(s_ndv, 1e-10f, 1.0f);
    float inv_sv = __builtin_amdgcn_rcpf(smith_view);

    F3 f0 = F3{metal*alb.x + (1.0f - metal)*0.04f,
               metal*alb.y + (1.0f - metal)*0.04f,
               metal*alb.z + (1.0f - metal)*0.04f};
    F3 kd = F3{alb.x*(1.0f - metal), alb.y*(1.0f - metal), alb.z*(1.0f - metal)};

    // VNDF frame (per-point in reference)
    F3 vh = norm3(F3{vl.x*alpha, vl.y*alpha, vl.z});
    F3 b1;
    float l2d = vh.x*vh.x + vh.y*vh.y;
    if (l2d <= 0.0f) b1 = F3{1.0f, 0.0f, 0.0f};
    else             b1 = norm3(F3{-vh.y, vh.x, 0.0f});
    F3 b2 = norm3(cross3(vh, b1));
    float sfac = 0.5f*(1.0f + vh.z);

    // ---- per-sample (one per lane) ----
    size_t si = (size_t)p*SN + lane;
    float U1 = u1_[si], U2 = u2_[si], UC = uc_[si], VC = vc_[si];

    // GGX VNDF sample; sin/cos of 2*pi*U via HW revolution-domain sin/cos
    float r = __builtin_amdgcn_sqrtf(U1);
    float sth = __builtin_amdgcn_sinf(U2);
    float cth = __builtin_amdgcn_cosf(U2);
    float t1 = r*cth;
    float t2 = r*sth;
    t2 = (1.0f - sfac)*__builtin_amdgcn_sqrtf(fmaxf(1.0f - t1*t1, 0.0f)) + sfac*t2;
    float t3 = __builtin_amdgcn_sqrtf(clampf(1.0f - t1*t1 - t2*t2, 0.0f, 1.0f));
    F3 mh = F3{t1*b1.x + t2*b2.x + t3*vh.x,
               t1*b1.y + t2*b2.y + t3*vh.y,
               t1*b1.z + t2*b2.z + t3*vh.z};
    F3 ml = norm3(F3{mh.x*alpha, mh.y*alpha, mh.z});
    // local -> world
    F3 m = F3{t.x*ml.x + b.x*ml.y + n.x*ml.z,
              t.y*ml.x + b.y*ml.y + n.y*ml.z,
              t.z*ml.x + b.z*ml.y + n.z*ml.z};
    // reflect view about m
    float idm = dot3(v, m);
    F3 light = norm3(F3{-v.x + 2.0f*idm*m.x,
                        -v.y + 2.0f*idm*m.y,
                        -v.z + 2.0f*idm*m.z});

    F3 rad = sample_env<TEX>(emap, tex, light);

    F3 hlf = norm3(F3{v.x + light.x, v.y + light.y, v.z + light.z});
    float hdv = clampf(dot3(hlf, v), 0.0f, 1.0f);
    float ndl = clampf(dot3(n, light), 0.0f, 1.0f);
    float s_ndl = smithf(alpha, ndl);
    float geom = s_ndv*s_ndl;
    float om = 1.0f - hdv;
    float om2 = om*om;
    float om5 = om2*om2*om;
    float gs = geom*inv_sv;

    F3 acc;
    acc.x = (f0.x + (1.0f - f0.x)*om5)*gs*rad.x;
    acc.y = (f0.y + (1.0f - f0.y)*om5)*gs*rad.y;
    acc.z = (f0.z + (1.0f - f0.z)*om5)*gs*rad.z;

    // cosine-hemisphere diffuse sample
    float sph = __builtin_amdgcn_sinf(UC);
    float cph = __builtin_amdgcn_cosf(UC);
    float ct = __builtin_amdgcn_sqrtf(VC);
    float st = __builtin_amdgcn_sqrtf(fmaxf(1.0f - VC, 0.0f));
    F3 ldl = F3{cph*st, sph*st, ct};
    F3 ld = F3{t.x*ldl.x + b.x*ldl.y + n.x*ldl.z,
               t.y*ldl.x + b.y*ldl.y + n.y*ldl.z,
               t.z*ldl.x + b.z*ldl.y + n.z*ldl.z};
    F3 radd = sample_env<TEX>(emap, tex, ld);

    acc.x += radd.x*kd.x;
    acc.y += radd.y*kd.y;
    acc.z += radd.z*kd.z;

    // mean over S via wave butterfly reduce
    acc.x = wave_sum(acc.x);
    acc.y = wave_sum(acc.y);
    acc.z = wave_sum(acc.z);

    if (lane == 0) {
        const float inv_s = 1.0f/(float)SN;
        out[3*p + 0] = acc.x*inv_s;
        out[3*p + 1] = acc.y*inv_s;
        out[3*p + 2] = acc.z*inv_s;
    }
}

} // anonymous namespace

extern "C" void kernel_launch(void* const* d_in, const int* in_sizes, int n_in,
                              void* d_out, int out_size, void* d_ws, size_t ws_size,
                              hipStream_t stream) {
    const float* emap     = (const float*)d_in[0];
    const float* view_dir = (const float*)d_in[1];
    const float* normal   = (const float*)d_in[2];
    const float* albedo   = (const float*)d_in[3];
    const float* rough    = (const float*)d_in[4];
    const float* metal    = (const float*)d_in[5];
    const float* u1       = (const float*)d_in[6];
    const float* u2       = (const float*)d_in[7];
    const float* uc       = (const float*)d_in[8];
    const float* vc       = (const float*)d_in[9];
    float* out            = (float*)d_out;

    const int HW = EH*EW;
    const size_t tex_bytes = (size_t)HW*sizeof(H4);
    const int main_blocks = PN*SN/256;  // one wave (64 lanes) per point, 4 points/block

    if (ws_size >= tex_bytes) {
        H4* tex = (H4*)d_ws;
        relayout_kernel<<<(HW + 255)/256, 256, 0, stream>>>(emap, tex);
        ibl_kernel<true><<<main_blocks, 256, 0, stream>>>(
            emap, tex, view_dir, normal, albedo, rough, metal, u1, u2, uc, vc, out);
    } else {
        ibl_kernel<false><<<main_blocks, 256, 0, stream>>>(
            emap, nullptr, view_dir, normal, albedo, rough, metal, u1, u2, uc, vc, out);
    }
}

// Round 3
// 205.113 us; speedup vs baseline: 1.5284x; 1.1226x over previous
//
#include <hip/hip_runtime.h>
#include <hip/hip_fp16.h>
#include <math.h>

namespace {

constexpr int PN = 131072;
constexpr int SN = 64;
constexpr int EH = 512;
constexpr int EW = 1024;
constexpr float SPI = 162.97466172610083f;  // 512/pi

struct F3 { float x, y, z; };

struct alignas(8) H4   { __half2 rg;  __half2 ba; };
struct alignas(8) H4x2 { __half2 rg0; __half2 ba0; __half2 rg1; __half2 ba1; };

__device__ __forceinline__ float dot3(F3 a, F3 b) { return a.x*b.x + a.y*b.y + a.z*b.z; }
__device__ __forceinline__ F3 cross3(F3 a, F3 b) {
    return F3{a.y*b.z - a.z*b.y, a.z*b.x - a.x*b.z, a.x*b.y - a.y*b.x};
}
__device__ __forceinline__ float clampf(float x, float lo, float hi) {
    return fminf(fmaxf(x, lo), hi);
}
__device__ __forceinline__ F3 norm3(F3 a) {
    float l2 = a.x*a.x + a.y*a.y + a.z*a.z;
    float inv = __builtin_amdgcn_rsqf(fmaxf(l2, 1e-24f));
    return F3{a.x*inv, a.y*inv, a.z*inv};
}
__device__ __forceinline__ float smithf(float alpha, float c) {
    float a2 = alpha*alpha;
    float den = c + __builtin_amdgcn_sqrtf(a2 + (1.0f - a2)*c*c);
    return 2.0f*c*__builtin_amdgcn_rcpf(den);
}

// atan2 via degree-11 odd minimax (abs err ~1e-6 rad)
__device__ __forceinline__ float fast_atan2(float y, float x) {
    float ax = fabsf(x), ay = fabsf(y);
    float mx = fmaxf(ax, ay), mn = fminf(ax, ay);
    float a = mn * __builtin_amdgcn_rcpf(mx);
    if (mx == 0.0f) a = 0.0f;
    float s = a*a;
    float p = fmaf(s, -0.01172120f, 0.05265332f);
    p = fmaf(s, p, -0.11643287f);
    p = fmaf(s, p,  0.19354346f);
    p = fmaf(s, p, -0.33262347f);
    p = fmaf(s, p,  0.99997726f);
    float r = p * a;
    if (ay > ax)  r = 1.57079632679f - r;
    if (x < 0.0f) r = 3.14159265359f - r;
    return copysignf(r, y);
}

// acos via sqrt*poly (abs err ~1e-6 rad); x pre-clamped to [-1,1]
__device__ __forceinline__ float fast_acos(float x) {
    float ax = fabsf(x);
    float p = fmaf(ax, -0.0012624911f, 0.0066700901f);
    p = fmaf(ax, p, -0.0170881256f);
    p = fmaf(ax, p,  0.0308918810f);
    p = fmaf(ax, p, -0.0501743046f);
    p = fmaf(ax, p,  0.0889789874f);
    p = fmaf(ax, p, -0.2145988016f);
    p = fmaf(ax, p,  1.5707963050f);
    float s = __builtin_amdgcn_sqrtf(fmaxf(1.0f - ax, 0.0f));
    float r = s * p;
    return (x >= 0.0f) ? r : 3.14159265359f - r;
}

// lat-long uv -> two row-pair texel indices + weights + border flags
__device__ __forceinline__ void env_addr(F3 d, int& i0, int& i1,
                                         float& wx, float& wy,
                                         bool& at_l, bool& at_r) {
    float t  = fast_atan2(d.x, -d.z);
    float vv = fast_acos(clampf(d.y, -1.0f, 1.0f));
    float x = fmaf(t,  SPI, 511.5f);   // u*W - 0.5
    float y = fmaf(vv, SPI, -0.5f);    // v*H - 0.5
    float x0f = floorf(x), y0f = floorf(y);
    wx = x - x0f; wy = y - y0f;
    int ix = (int)x0f, iy = (int)y0f;
    int xb = min(max(ix, 0), EW - 2);          // pair base: texels xb, xb+1 (in-row)
    int y0 = min(max(iy, 0), EH - 1);
    int y1 = min(max(iy + 1, 0), EH - 1);
    at_l = ix < 0;          // both taps -> texel 0   (pair lo)
    at_r = ix >= EW - 1;    // both taps -> texel W-1 (pair hi)
    i0 = (y0 << 10) + xb;
    i1 = (y1 << 10) + xb;
}

__device__ __forceinline__ F3 env_blend(H4x2 r0, H4x2 r1, float wx, float wy,
                                        bool at_l, bool at_r) {
    __half2 l0rg = at_r ? r0.rg1 : r0.rg0;
    __half2 h0rg = at_l ? r0.rg0 : r0.rg1;
    __half2 l0ba = at_r ? r0.ba1 : r0.ba0;
    __half2 h0ba = at_l ? r0.ba0 : r0.ba1;
    __half2 l1rg = at_r ? r1.rg1 : r1.rg0;
    __half2 h1rg = at_l ? r1.rg0 : r1.rg1;
    __half2 l1ba = at_r ? r1.ba1 : r1.ba0;
    __half2 h1ba = at_l ? r1.ba0 : r1.ba1;
    float2 a0 = __half22float2(l0rg), b0 = __half22float2(h0rg);
    float2 a1 = __half22float2(l1rg), b1 = __half22float2(h1rg);
    float a0b = __half2float(__low2half(l0ba)), b0b = __half2float(__low2half(h0ba));
    float a1b = __half2float(__low2half(l1ba)), b1b = __half2float(__low2half(h1ba));
    // horizontal lerp per row, then vertical lerp
    float r0x = fmaf(wx, b0.x - a0.x, a0.x);
    float r0y = fmaf(wx, b0.y - a0.y, a0.y);
    float r0z = fmaf(wx, b0b - a0b, a0b);
    float r1x = fmaf(wx, b1.x - a1.x, a1.x);
    float r1y = fmaf(wx, b1.y - a1.y, a1.y);
    float r1z = fmaf(wx, b1b - a1b, a1b);
    return F3{fmaf(wy, r1x - r0x, r0x),
              fmaf(wy, r1y - r0y, r0y),
              fmaf(wy, r1z - r0z, r0z)};
}

__device__ __forceinline__ float wave_sum(float x) {
    #pragma unroll
    for (int m = 32; m >= 1; m >>= 1) x += __shfl_xor(x, m, 64);
    return x;
}

__global__ void relayout_kernel(const float* __restrict__ img, H4* __restrict__ tex) {
    int i = blockIdx.x*blockDim.x + threadIdx.x;
    const int HW = EH*EW;
    if (i < HW) {
        H4 h;
        h.rg = __floats2half2_rn(img[i], img[HW + i]);
        h.ba = __floats2half2_rn(img[2*HW + i], 0.0f);
        tex[i] = h;
    }
}

template<bool TEX>
__global__ __launch_bounds__(256, 8) void ibl_kernel(
    const float* __restrict__ emap, const H4* __restrict__ tex,
    const float* __restrict__ view_dir, const float* __restrict__ normal,
    const float* __restrict__ albedo, const float* __restrict__ rough_,
    const float* __restrict__ metal_, const float* __restrict__ u1_,
    const float* __restrict__ u2_, const float* __restrict__ uc_,
    const float* __restrict__ vc_, float* __restrict__ out)
{
    int gtid = blockIdx.x*blockDim.x + threadIdx.x;
    int p = gtid >> 6;            // one wave per point
    int lane = threadIdx.x & 63;  // one lane per sample
    if (p >= PN) return;

    // ---- streamed read-once inputs: non-temporal (keep texture L2-resident) ----
    size_t si = (size_t)p*SN + lane;
    float U1 = __builtin_nontemporal_load(u1_ + si);
    float U2 = __builtin_nontemporal_load(u2_ + si);
    float UC = __builtin_nontemporal_load(uc_ + si);
    float VC = __builtin_nontemporal_load(vc_ + si);

    F3 v   = F3{__builtin_nontemporal_load(view_dir + 3*p),
                __builtin_nontemporal_load(view_dir + 3*p + 1),
                __builtin_nontemporal_load(view_dir + 3*p + 2)};
    F3 n   = F3{__builtin_nontemporal_load(normal + 3*p),
                __builtin_nontemporal_load(normal + 3*p + 1),
                __builtin_nontemporal_load(normal + 3*p + 2)};
    F3 alb = F3{__builtin_nontemporal_load(albedo + 3*p),
                __builtin_nontemporal_load(albedo + 3*p + 1),
                __builtin_nontemporal_load(albedo + 3*p + 2)};
    float rough = __builtin_nontemporal_load(rough_ + p);
    float metal = __builtin_nontemporal_load(metal_ + p);
    float alpha = rough*rough;

    // ---- TBN (rows: tangent, bitangent, normal) ----
    F3 t;
    float nx2nz2 = n.x*n.x + n.z*n.z;
    if (nx2nz2 <= 0.0f) t = F3{1.0f, 0.0f, 0.0f};
    else                t = norm3(F3{n.z, 0.0f, -n.x});
    F3 b = cross3(n, t);   // unit to ~1e-7 (t ⟂ n by construction)

    // ---- diffuse sample: short chain, issue its gathers FIRST ----
    float sph = __builtin_amdgcn_sinf(UC);
    float cph = __builtin_amdgcn_cosf(UC);
    float ct = __builtin_amdgcn_sqrtf(VC);
    float st = __builtin_amdgcn_sqrtf(fmaxf(1.0f - VC, 0.0f));
    F3 ldl = F3{cph*st, sph*st, ct};
    F3 ld = F3{t.x*ldl.x + b.x*ldl.y + n.x*ldl.z,
               t.y*ldl.x + b.y*ldl.y + n.y*ldl.z,
               t.z*ldl.x + b.z*ldl.y + n.z*ldl.z};
    int di0, di1; float dwx, dwy; bool d_l, d_r;
    H4x2 dr0, dr1;
    if (TEX) {
        env_addr(ld, di0, di1, dwx, dwy, d_l, d_r);
        dr0 = *reinterpret_cast<const H4x2*>(tex + di0);
        dr1 = *reinterpret_cast<const H4x2*>(tex + di1);
    }

    // ---- spec chain (VALU hides diffuse-load latency) ----
    F3 vl = F3{dot3(t, v), dot3(b, v), dot3(n, v)};
    float ndv = clampf(vl.z, 0.0f, 1.0f);   // n·v == vl.z
    float s_ndv = smithf(alpha, ndv);
    float inv_sv = __builtin_amdgcn_rcpf(clampf(s_ndv, 1e-10f, 1.0f));
    float sv_ratio = s_ndv * inv_sv;

    F3 vh = norm3(F3{vl.x*alpha, vl.y*alpha, vl.z});
    F3 b1;
    float l2d = vh.x*vh.x + vh.y*vh.y;
    if (l2d <= 0.0f) b1 = F3{1.0f, 0.0f, 0.0f};
    else             b1 = norm3(F3{-vh.y, vh.x, 0.0f});
    F3 b2 = cross3(vh, b1);   // unit to ~1e-7
    float sfac = 0.5f*(1.0f + vh.z);

    float r = __builtin_amdgcn_sqrtf(U1);
    float sth = __builtin_amdgcn_sinf(U2);
    float cth = __builtin_amdgcn_cosf(U2);
    float t1 = r*cth;
    float t2 = r*sth;
    t2 = (1.0f - sfac)*__builtin_amdgcn_sqrtf(fmaxf(1.0f - t1*t1, 0.0f)) + sfac*t2;
    float t3 = __builtin_amdgcn_sqrtf(clampf(1.0f - t1*t1 - t2*t2, 0.0f, 1.0f));
    F3 mh = F3{t1*b1.x + t2*b2.x + t3*vh.x,
               t1*b1.y + t2*b2.y + t3*vh.y,
               t1*b1.z + t2*b2.z + t3*vh.z};
    F3 ml = norm3(F3{mh.x*alpha, mh.y*alpha, mh.z});
    F3 m = F3{t.x*ml.x + b.x*ml.y + n.x*ml.z,
              t.y*ml.x + b.y*ml.y + n.y*ml.z,
              t.z*ml.x + b.z*ml.y + n.z*ml.z};
    float idm = dot3(v, m);
    F3 light = F3{fmaf(2.0f*idm, m.x, -v.x),
                  fmaf(2.0f*idm, m.y, -v.y),
                  fmaf(2.0f*idm, m.z, -v.z)};   // unit reflect of unit v

    int si0, si1; float swx, swy; bool s_l, s_r;
    H4x2 sr0, sr1;
    if (TEX) {
        env_addr(light, si0, si1, swx, swy, s_l, s_r);
        sr0 = *reinterpret_cast<const H4x2*>(tex + si0);
        sr1 = *reinterpret_cast<const H4x2*>(tex + si1);
    }

    // ---- shading scalars (hide spec-load latency) ----
    F3 hlf = norm3(F3{v.x + light.x, v.y + light.y, v.z + light.z});
    float hdv = clampf(dot3(hlf, v), 0.0f, 1.0f);
    float ndl = clampf(dot3(n, light), 0.0f, 1.0f);
    float s_ndl = smithf(alpha, ndl);
    float gs = sv_ratio * s_ndl;    // smith(ndv)*smith(ndl)/clip(smith(ndv))
    float om = 1.0f - hdv;
    float om2 = om*om;
    float om5 = om2*om2*om;
    F3 f0 = F3{metal*alb.x + (1.0f - metal)*0.04f,
               metal*alb.y + (1.0f - metal)*0.04f,
               metal*alb.z + (1.0f - metal)*0.04f};
    F3 kd = F3{alb.x*(1.0f - metal), alb.y*(1.0f - metal), alb.z*(1.0f - metal)};

    // ---- blends ----
    F3 rad, radd;
    if (TEX) {
        radd = env_blend(dr0, dr1, dwx, dwy, d_l, d_r);
        rad  = env_blend(sr0, sr1, swx, swy, s_l, s_r);
    } else {
        const int HW = EH*EW;
        #pragma unroll
        for (int pass = 0; pass < 2; ++pass) {
            F3 d = pass ? light : ld;
            int i0, i1; float wx, wy; bool atl, atr;
            env_addr(d, i0, i1, wx, wy, atl, atr);
            int x0 = atr ? 1 : 0, x1 = atl ? 0 : 1;
            F3 o;
            float* po = &o.x;
            #pragma unroll
            for (int c = 0; c < 3; ++c) {
                const float* pl = emap + c*HW;
                float v00 = pl[i0 + x0], v01 = pl[i0 + x1];
                float v10 = pl[i1 + x0], v11 = pl[i1 + x1];
                float rr0 = fmaf(wx, v01 - v00, v00);
                float rr1 = fmaf(wx, v11 - v10, v10);
                po[c] = fmaf(wy, rr1 - rr0, rr0);
            }
            if (pass) rad = o; else radd = o;
        }
    }

    F3 acc;
    acc.x = fmaf((f0.x + (1.0f - f0.x)*om5)*gs, rad.x, radd.x*kd.x);
    acc.y = fmaf((f0.y + (1.0f - f0.y)*om5)*gs, rad.y, radd.y*kd.y);
    acc.z = fmaf((f0.z + (1.0f - f0.z)*om5)*gs, rad.z, radd.z*kd.z);

    // ---- mean over S via wave butterfly ----
    acc.x = wave_sum(acc.x);
    acc.y = wave_sum(acc.y);
    acc.z = wave_sum(acc.z);

    if (lane == 0) {
        const float inv_s = 1.0f/(float)SN;
        __builtin_nontemporal_store(acc.x*inv_s, out + 3*p + 0);
        __builtin_nontemporal_store(acc.y*inv_s, out + 3*p + 1);
        __builtin_nontemporal_store(acc.z*inv_s, out + 3*p + 2);
    }
}

} // anonymous namespace

extern "C" void kernel_launch(void* const* d_in, const int* in_sizes, int n_in,
                              void* d_out, int out_size, void* d_ws, size_t ws_size,
                              hipStream_t stream) {
    const float* emap     = (const float*)d_in[0];
    const float* view_dir = (const float*)d_in[1];
    const float* normal   = (const float*)d_in[2];
    const float* albedo   = (const float*)d_in[3];
    const float* rough    = (const float*)d_in[4];
    const float* metal    = (const float*)d_in[5];
    const float* u1       = (const float*)d_in[6];
    const float* u2       = (const float*)d_in[7];
    const float* uc       = (const float*)d_in[8];
    const float* vc       = (const float*)d_in[9];
    float* out            = (float*)d_out;

    const int HW = EH*EW;
    const size_t tex_bytes = (size_t)HW*sizeof(H4);
    const int main_blocks = PN*SN/256;  // one wave (64 lanes) per point

    if (ws_size >= tex_bytes) {
        H4* tex = (H4*)d_ws;
        relayout_kernel<<<(HW + 255)/256, 256, 0, stream>>>(emap, tex);
        ibl_kernel<true><<<main_blocks, 256, 0, stream>>>(
            emap, tex, view_dir, normal, albedo, rough, metal, u1, u2, uc, vc, out);
    } else {
        ibl_kernel<false><<<main_blocks, 256, 0, stream>>>(
            emap, nullptr, view_dir, normal, albedo, rough, metal, u1, u2, uc, vc, out);
    }
}

// Round 4
// 153.968 us; speedup vs baseline: 2.0361x; 1.3322x over previous
//
#include <hip/hip_runtime.h>
#include <math.h>

namespace {

constexpr int PN = 131072;
constexpr int SN = 64;
constexpr int EH = 512;
constexpr int EW = 1024;
constexpr float SPI = 162.97466172610083f;  // 512/pi

struct F3 { float x, y, z; };

__device__ __forceinline__ float dot3(F3 a, F3 b) { return a.x*b.x + a.y*b.y + a.z*b.z; }
__device__ __forceinline__ F3 cross3(F3 a, F3 b) {
    return F3{a.y*b.z - a.z*b.y, a.z*b.x - a.x*b.z, a.x*b.y - a.y*b.x};
}
__device__ __forceinline__ float clampf(float x, float lo, float hi) {
    return fminf(fmaxf(x, lo), hi);
}
__device__ __forceinline__ F3 norm3(F3 a) {
    float l2 = a.x*a.x + a.y*a.y + a.z*a.z;
    float inv = __builtin_amdgcn_rsqf(fmaxf(l2, 1e-24f));
    return F3{a.x*inv, a.y*inv, a.z*inv};
}
__device__ __forceinline__ float smithf(float alpha, float c) {
    float a2 = alpha*alpha;
    float den = c + __builtin_amdgcn_sqrtf(a2 + (1.0f - a2)*c*c);
    return 2.0f*c*__builtin_amdgcn_rcpf(den);
}

// atan2 via degree-11 odd minimax (abs err ~1e-6 rad)
__device__ __forceinline__ float fast_atan2(float y, float x) {
    float ax = fabsf(x), ay = fabsf(y);
    float mx = fmaxf(ax, ay), mn = fminf(ax, ay);
    float a = mn * __builtin_amdgcn_rcpf(mx);
    if (mx == 0.0f) a = 0.0f;
    float s = a*a;
    float p = fmaf(s, -0.01172120f, 0.05265332f);
    p = fmaf(s, p, -0.11643287f);
    p = fmaf(s, p,  0.19354346f);
    p = fmaf(s, p, -0.33262347f);
    p = fmaf(s, p,  0.99997726f);
    float r = p * a;
    if (ay > ax)  r = 1.57079632679f - r;
    if (x < 0.0f) r = 3.14159265359f - r;
    return copysignf(r, y);
}

// acos via sqrt*poly (abs err ~1e-6 rad); x pre-clamped to [-1,1]
__device__ __forceinline__ float fast_acos(float x) {
    float ax = fabsf(x);
    float p = fmaf(ax, -0.0012624911f, 0.0066700901f);
    p = fmaf(ax, p, -0.0170881256f);
    p = fmaf(ax, p,  0.0308918810f);
    p = fmaf(ax, p, -0.0501743046f);
    p = fmaf(ax, p,  0.0889789874f);
    p = fmaf(ax, p, -0.2145988016f);
    p = fmaf(ax, p,  1.5707963050f);
    float s = __builtin_amdgcn_sqrtf(fmaxf(1.0f - ax, 0.0f));
    float r = s * p;
    return (x >= 0.0f) ? r : 3.14159265359f - r;
}

// lat-long uv -> two row-pair texel indices + weights + border flags
__device__ __forceinline__ void env_addr(F3 d, int& i0, int& i1,
                                         float& wx, float& wy,
                                         bool& at_l, bool& at_r) {
    float t  = fast_atan2(d.x, -d.z);
    float vv = fast_acos(clampf(d.y, -1.0f, 1.0f));
    float x = fmaf(t,  SPI, 511.5f);   // u*W - 0.5
    float y = fmaf(vv, SPI, -0.5f);    // v*H - 0.5
    float x0f = floorf(x), y0f = floorf(y);
    wx = x - x0f; wy = y - y0f;
    int ix = (int)x0f, iy = (int)y0f;
    int xb = min(max(ix, 0), EW - 2);          // pair base: texels xb, xb+1
    int y0 = min(max(iy, 0), EH - 1);
    int y1 = min(max(iy + 1, 0), EH - 1);
    at_l = ix < 0;          // both taps -> pair lo
    at_r = ix >= EW - 1;    // both taps -> pair hi
    i0 = (y0 << 10) + xb;
    i1 = (y1 << 10) + xb;
}

// RGB9E5: value = mant * 2^(e-24); accumulate w * texel into acc
__device__ __forceinline__ void rgb9e5_addmul(unsigned int v, float w, F3& acc) {
    float scale = __uint_as_float(((v >> 27) + 103u) << 23);  // 2^(e-24)
    float ws = w * scale;
    acc.x = fmaf((float)(v & 511u), ws, acc.x);
    acc.y = fmaf((float)((v >> 9) & 511u), ws, acc.y);
    acc.z = fmaf((float)((v >> 18) & 511u), ws, acc.z);
}

__device__ __forceinline__ F3 env_blend9(uint2 r0, uint2 r1, float wx, float wy,
                                         bool at_l, bool at_r) {
    unsigned int t00 = at_r ? r0.y : r0.x;
    unsigned int t01 = at_l ? r0.x : r0.y;
    unsigned int t10 = at_r ? r1.y : r1.x;
    unsigned int t11 = at_l ? r1.x : r1.y;
    float w00 = (1.0f - wx)*(1.0f - wy);
    float w01 = wx*(1.0f - wy);
    float w10 = (1.0f - wx)*wy;
    float w11 = wx*wy;
    F3 acc{0.0f, 0.0f, 0.0f};
    rgb9e5_addmul(t00, w00, acc);
    rgb9e5_addmul(t01, w01, acc);
    rgb9e5_addmul(t10, w10, acc);
    rgb9e5_addmul(t11, w11, acc);
    return acc;
}

__device__ __forceinline__ float wave_sum(float x) {
    #pragma unroll
    for (int m = 32; m >= 1; m >>= 1) x += __shfl_xor(x, m, 64);
    return x;
}

__global__ void relayout_kernel(const float* __restrict__ img, unsigned int* __restrict__ tex) {
    int i = blockIdx.x*blockDim.x + threadIdx.x;
    const int HW = EH*EW;
    if (i < HW) {
        float r = img[i], g = img[HW + i], b = img[2*HW + i];
        float m = fmaxf(fmaxf(r, g), b);
        int es = min(max((int)(__float_as_uint(m) >> 23) - 111, 0), 31);
        float sc = __uint_as_float((unsigned int)(151 - es) << 23);   // 2^(24-es)
        unsigned int R = min(511u, (unsigned int)rintf(r*sc));
        unsigned int G = min(511u, (unsigned int)rintf(g*sc));
        unsigned int B = min(511u, (unsigned int)rintf(b*sc));
        tex[i] = ((unsigned int)es << 27) | (B << 18) | (G << 9) | R;
    }
}

template<bool TEX>
__global__ __launch_bounds__(256) void ibl_kernel(
    const float* __restrict__ emap, const unsigned int* __restrict__ tex,
    const float* __restrict__ view_dir, const float* __restrict__ normal,
    const float* __restrict__ albedo, const float* __restrict__ rough_,
    const float* __restrict__ metal_, const float* __restrict__ u1_,
    const float* __restrict__ u2_, const float* __restrict__ uc_,
    const float* __restrict__ vc_, float* __restrict__ out)
{
    int lane = threadIdx.x & 63;
    int wid  = (blockIdx.x << 2) + (threadIdx.x >> 6);   // wave id
    int p0   = __builtin_amdgcn_readfirstlane(wid << 1); // 2 points per wave, uniform

    // ---- streamed per-sample inputs (non-temporal; keep texture L2-resident) ----
    float U1[2], U2[2], UC[2], VC[2];
    F3 v[2], n[2], alb[2];
    float alpha[2], metal[2];
    #pragma unroll
    for (int k = 0; k < 2; ++k) {
        int p = p0 + k;
        size_t si = (size_t)p*SN + lane;
        U1[k] = __builtin_nontemporal_load(u1_ + si);
        U2[k] = __builtin_nontemporal_load(u2_ + si);
        UC[k] = __builtin_nontemporal_load(uc_ + si);
        VC[k] = __builtin_nontemporal_load(vc_ + si);
        v[k]   = F3{view_dir[3*p], view_dir[3*p+1], view_dir[3*p+2]};
        n[k]   = F3{normal[3*p],   normal[3*p+1],   normal[3*p+2]};
        alb[k] = F3{albedo[3*p],   albedo[3*p+1],   albedo[3*p+2]};
        float rg = rough_[p];
        alpha[k] = rg*rg;
        metal[k] = metal_[p];
    }

    // ---- per-point frames ----
    F3 t[2], b[2];
    #pragma unroll
    for (int k = 0; k < 2; ++k) {
        float nx2nz2 = n[k].x*n[k].x + n[k].z*n[k].z;
        if (nx2nz2 <= 0.0f) t[k] = F3{1.0f, 0.0f, 0.0f};
        else                t[k] = norm3(F3{n[k].z, 0.0f, -n[k].x});
        b[k] = cross3(n[k], t[k]);   // unit to ~1e-7
    }

    // ---- diffuse dirs: short chain, issue gathers FIRST ----
    uint2 dr0[2], dr1[2];
    float dwx[2], dwy[2];
    bool d_l[2], d_r[2];
    F3 ld[2];
    #pragma unroll
    for (int k = 0; k < 2; ++k) {
        float sph = __builtin_amdgcn_sinf(UC[k]);
        float cph = __builtin_amdgcn_cosf(UC[k]);
        float ct = __builtin_amdgcn_sqrtf(VC[k]);
        float st = __builtin_amdgcn_sqrtf(fmaxf(1.0f - VC[k], 0.0f));
        F3 ldl = F3{cph*st, sph*st, ct};
        ld[k] = F3{t[k].x*ldl.x + b[k].x*ldl.y + n[k].x*ldl.z,
                   t[k].y*ldl.x + b[k].y*ldl.y + n[k].y*ldl.z,
                   t[k].z*ldl.x + b[k].z*ldl.y + n[k].z*ldl.z};
        if (TEX) {
            int i0, i1;
            env_addr(ld[k], i0, i1, dwx[k], dwy[k], d_l[k], d_r[k]);
            dr0[k] = *reinterpret_cast<const uint2*>(tex + i0);
            dr1[k] = *reinterpret_cast<const uint2*>(tex + i1);
        }
    }

    // ---- spec chains (VALU hides diffuse-load latency) ----
    uint2 sr0[2], sr1[2];
    float swx[2], swy[2];
    bool s_l[2], s_r[2];
    F3 light[2];
    float sv_ratio[2], s_ndv_a[2];
    #pragma unroll
    for (int k = 0; k < 2; ++k) {
        F3 vl = F3{dot3(t[k], v[k]), dot3(b[k], v[k]), dot3(n[k], v[k])};
        float ndv = clampf(vl.z, 0.0f, 1.0f);
        float s_ndv = smithf(alpha[k], ndv);
        float inv_sv = __builtin_amdgcn_rcpf(clampf(s_ndv, 1e-10f, 1.0f));
        sv_ratio[k] = s_ndv * inv_sv;
        s_ndv_a[k] = s_ndv;

        F3 vh = norm3(F3{vl.x*alpha[k], vl.y*alpha[k], vl.z});
        F3 b1;
        float l2d = vh.x*vh.x + vh.y*vh.y;
        if (l2d <= 0.0f) b1 = F3{1.0f, 0.0f, 0.0f};
        else             b1 = norm3(F3{-vh.y, vh.x, 0.0f});
        F3 b2 = cross3(vh, b1);
        float sfac = 0.5f*(1.0f + vh.z);

        float r = __builtin_amdgcn_sqrtf(U1[k]);
        float sth = __builtin_amdgcn_sinf(U2[k]);
        float cth = __builtin_amdgcn_cosf(U2[k]);
        float t1 = r*cth;
        float t2 = r*sth;
        t2 = (1.0f - sfac)*__builtin_amdgcn_sqrtf(fmaxf(1.0f - t1*t1, 0.0f)) + sfac*t2;
        float t3 = __builtin_amdgcn_sqrtf(clampf(1.0f - t1*t1 - t2*t2, 0.0f, 1.0f));
        F3 mh = F3{t1*b1.x + t2*b2.x + t3*vh.x,
                   t1*b1.y + t2*b2.y + t3*vh.y,
                   t1*b1.z + t2*b2.z + t3*vh.z};
        F3 ml = norm3(F3{mh.x*alpha[k], mh.y*alpha[k], mh.z});
        F3 m = F3{t[k].x*ml.x + b[k].x*ml.y + n[k].x*ml.z,
                  t[k].y*ml.x + b[k].y*ml.y + n[k].y*ml.z,
                  t[k].z*ml.x + b[k].z*ml.y + n[k].z*ml.z};
        float idm = dot3(v[k], m);
        light[k] = F3{fmaf(2.0f*idm, m.x, -v[k].x),
                      fmaf(2.0f*idm, m.y, -v[k].y),
                      fmaf(2.0f*idm, m.z, -v[k].z)};
        if (TEX) {
            int i0, i1;
            env_addr(light[k], i0, i1, swx[k], swy[k], s_l[k], s_r[k]);
            sr0[k] = *reinterpret_cast<const uint2*>(tex + i0);
            sr1[k] = *reinterpret_cast<const uint2*>(tex + i1);
        }
    }

    // ---- shading scalars (hide spec-load latency) ----
    F3 f0[2], kd[2];
    float fresc[2];   // gs
    float om5[2];
    #pragma unroll
    for (int k = 0; k < 2; ++k) {
        F3 hlf = norm3(F3{v[k].x + light[k].x, v[k].y + light[k].y, v[k].z + light[k].z});
        float hdv = clampf(dot3(hlf, v[k]), 0.0f, 1.0f);
        float ndl = clampf(dot3(n[k], light[k]), 0.0f, 1.0f);
        float s_ndl = smithf(alpha[k], ndl);
        fresc[k] = sv_ratio[k] * s_ndl;
        float om = 1.0f - hdv;
        float om2 = om*om;
        om5[k] = om2*om2*om;
        f0[k] = F3{metal[k]*alb[k].x + (1.0f - metal[k])*0.04f,
                   metal[k]*alb[k].y + (1.0f - metal[k])*0.04f,
                   metal[k]*alb[k].z + (1.0f - metal[k])*0.04f};
        kd[k] = F3{alb[k].x*(1.0f - metal[k]), alb[k].y*(1.0f - metal[k]),
                   alb[k].z*(1.0f - metal[k])};
    }

    // ---- blends + output ----
    #pragma unroll
    for (int k = 0; k < 2; ++k) {
        F3 rad, radd;
        if (TEX) {
            radd = env_blend9(dr0[k], dr1[k], dwx[k], dwy[k], d_l[k], d_r[k]);
            rad  = env_blend9(sr0[k], sr1[k], swx[k], swy[k], s_l[k], s_r[k]);
        } else {
            const int HW = EH*EW;
            #pragma unroll
            for (int pass = 0; pass < 2; ++pass) {
                F3 d = pass ? light[k] : ld[k];
                int i0, i1; float wx, wy; bool atl, atr;
                env_addr(d, i0, i1, wx, wy, atl, atr);
                int x0 = atr ? 1 : 0, x1 = atl ? 0 : 1;
                F3 o;
                float* po = &o.x;
                #pragma unroll
                for (int c = 0; c < 3; ++c) {
                    const float* pl = emap + c*HW;
                    float v00 = pl[i0 + x0], v01 = pl[i0 + x1];
                    float v10 = pl[i1 + x0], v11 = pl[i1 + x1];
                    float rr0 = fmaf(wx, v01 - v00, v00);
                    float rr1 = fmaf(wx, v11 - v10, v10);
                    po[c] = fmaf(wy, rr1 - rr0, rr0);
                }
                if (pass) rad = o; else radd = o;
            }
        }
        float gs = fresc[k];
        F3 acc;
        acc.x = fmaf((f0[k].x + (1.0f - f0[k].x)*om5[k])*gs, rad.x, radd.x*kd[k].x);
        acc.y = fmaf((f0[k].y + (1.0f - f0[k].y)*om5[k])*gs, rad.y, radd.y*kd[k].y);
        acc.z = fmaf((f0[k].z + (1.0f - f0[k].z)*om5[k])*gs, rad.z, radd.z*kd[k].z);

        acc.x = wave_sum(acc.x);
        acc.y = wave_sum(acc.y);
        acc.z = wave_sum(acc.z);

        if (lane == 0) {
            const float inv_s = 1.0f/(float)SN;
            int p = p0 + k;
            __builtin_nontemporal_store(acc.x*inv_s, out + 3*p + 0);
            __builtin_nontemporal_store(acc.y*inv_s, out + 3*p + 1);
            __builtin_nontemporal_store(acc.z*inv_s, out + 3*p + 2);
        }
    }
}

} // anonymous namespace

extern "C" void kernel_launch(void* const* d_in, const int* in_sizes, int n_in,
                              void* d_out, int out_size, void* d_ws, size_t ws_size,
                              hipStream_t stream) {
    const float* emap     = (const float*)d_in[0];
    const float* view_dir = (const float*)d_in[1];
    const float* normal   = (const float*)d_in[2];
    const float* albedo   = (const float*)d_in[3];
    const float* rough    = (const float*)d_in[4];
    const float* metal    = (const float*)d_in[5];
    const float* u1       = (const float*)d_in[6];
    const float* u2       = (const float*)d_in[7];
    const float* uc       = (const float*)d_in[8];
    const float* vc       = (const float*)d_in[9];
    float* out            = (float*)d_out;

    const int HW = EH*EW;
    const size_t tex_bytes = (size_t)HW*sizeof(unsigned int);
    const int main_blocks = PN/8;   // 4 waves/block x 2 points/wave

    if (ws_size >= tex_bytes) {
        unsigned int* tex = (unsigned int*)d_ws;
        relayout_kernel<<<(HW + 255)/256, 256, 0, stream>>>(emap, tex);
        ibl_kernel<true><<<main_blocks, 256, 0, stream>>>(
            emap, tex, view_dir, normal, albedo, rough, metal, u1, u2, uc, vc, out);
    } else {
        ibl_kernel<false><<<main_blocks, 256, 0, stream>>>(
            emap, nullptr, view_dir, normal, albedo, rough, metal, u1, u2, uc, vc, out);
    }
}

// Round 6
// 153.516 us; speedup vs baseline: 2.0421x; 1.0029x over previous
//
#include <hip/hip_runtime.h>
#include <math.h>

namespace {

constexpr int PN = 131072;
constexpr int SN = 64;
constexpr int EH = 512;
constexpr int EW = 1024;
constexpr float SPI = 162.97466172610083f;  // 512/pi

struct F3 { float x, y, z; };

__device__ __forceinline__ float dot3(F3 a, F3 b) { return a.x*b.x + a.y*b.y + a.z*b.z; }
__device__ __forceinline__ F3 cross3(F3 a, F3 b) {
    return F3{a.y*b.z - a.z*b.y, a.z*b.x - a.x*b.z, a.x*b.y - a.y*b.x};
}
__device__ __forceinline__ float clampf(float x, float lo, float hi) {
    return fminf(fmaxf(x, lo), hi);
}
__device__ __forceinline__ F3 norm3(F3 a) {
    float l2 = a.x*a.x + a.y*a.y + a.z*a.z;
    float inv = __builtin_amdgcn_rsqf(fmaxf(l2, 1e-24f));
    return F3{a.x*inv, a.y*inv, a.z*inv};
}
__device__ __forceinline__ float smithf(float alpha, float c) {
    float a2 = alpha*alpha;
    float den = c + __builtin_amdgcn_sqrtf(a2 + (1.0f - a2)*c*c);
    return 2.0f*c*__builtin_amdgcn_rcpf(den);
}

// atan2 via degree-11 odd minimax (abs err ~1e-6 rad)
__device__ __forceinline__ float fast_atan2(float y, float x) {
    float ax = fabsf(x), ay = fabsf(y);
    float mx = fmaxf(ax, ay), mn = fminf(ax, ay);
    float a = mn * __builtin_amdgcn_rcpf(mx);
    if (mx == 0.0f) a = 0.0f;
    float s = a*a;
    float p = fmaf(s, -0.01172120f, 0.05265332f);
    p = fmaf(s, p, -0.11643287f);
    p = fmaf(s, p,  0.19354346f);
    p = fmaf(s, p, -0.33262347f);
    p = fmaf(s, p,  0.99997726f);
    float r = p * a;
    if (ay > ax)  r = 1.57079632679f - r;
    if (x < 0.0f) r = 3.14159265359f - r;
    return copysignf(r, y);
}

// acos via sqrt*poly (abs err ~1e-6 rad); x pre-clamped to [-1,1]
__device__ __forceinline__ float fast_acos(float x) {
    float ax = fabsf(x);
    float p = fmaf(ax, -0.0012624911f, 0.0066700901f);
    p = fmaf(ax, p, -0.0170881256f);
    p = fmaf(ax, p,  0.0308918810f);
    p = fmaf(ax, p, -0.0501743046f);
    p = fmaf(ax, p,  0.0889789874f);
    p = fmaf(ax, p, -0.2145988016f);
    p = fmaf(ax, p,  1.5707963050f);
    float s = __builtin_amdgcn_sqrtf(fmaxf(1.0f - ax, 0.0f));
    float r = s * p;
    return (x >= 0.0f) ? r : 3.14159265359f - r;
}

// lat-long uv -> two row-pair texel indices + weights + border flags
__device__ __forceinline__ void env_addr(F3 d, int& i0, int& i1,
                                         float& wx, float& wy,
                                         bool& at_l, bool& at_r) {
    float t  = fast_atan2(d.x, -d.z);
    float vv = fast_acos(clampf(d.y, -1.0f, 1.0f));
    float x = fmaf(t,  SPI, 511.5f);   // u*W - 0.5
    float y = fmaf(vv, SPI, -0.5f);    // v*H - 0.5
    float x0f = floorf(x), y0f = floorf(y);
    wx = x - x0f; wy = y - y0f;
    int ix = (int)x0f, iy = (int)y0f;
    int xb = min(max(ix, 0), EW - 2);          // pair base: texels xb, xb+1
    int y0 = min(max(iy, 0), EH - 1);
    int y1 = min(max(iy + 1, 0), EH - 1);
    at_l = ix < 0;          // both taps -> pair lo
    at_r = ix >= EW - 1;    // both taps -> pair hi
    i0 = (y0 << 10) + xb;
    i1 = (y1 << 10) + xb;
}

// RGB9E5: value = mant * 2^(e-24); accumulate w * texel into acc
__device__ __forceinline__ void rgb9e5_addmul(unsigned int v, float w, F3& acc) {
    float scale = __uint_as_float(((v >> 27) + 103u) << 23);  // 2^(e-24)
    float ws = w * scale;
    acc.x = fmaf((float)(v & 511u), ws, acc.x);
    acc.y = fmaf((float)((v >> 9) & 511u), ws, acc.y);
    acc.z = fmaf((float)((v >> 18) & 511u), ws, acc.z);
}

__device__ __forceinline__ F3 env_blend9(uint2 r0, uint2 r1, float wx, float wy,
                                         bool at_l, bool at_r) {
    unsigned int t00 = at_r ? r0.y : r0.x;
    unsigned int t01 = at_l ? r0.x : r0.y;
    unsigned int t10 = at_r ? r1.y : r1.x;
    unsigned int t11 = at_l ? r1.x : r1.y;
    float w00 = (1.0f - wx)*(1.0f - wy);
    float w01 = wx*(1.0f - wy);
    float w10 = (1.0f - wx)*wy;
    float w11 = wx*wy;
    F3 acc{0.0f, 0.0f, 0.0f};
    rgb9e5_addmul(t00, w00, acc);
    rgb9e5_addmul(t01, w01, acc);
    rgb9e5_addmul(t10, w10, acc);
    rgb9e5_addmul(t11, w11, acc);
    return acc;
}

// ---- wave64 sum via DPP (no LDS pipe); compile-time DPP controls ----
template<int CTRL, int ROW_MASK, bool BC>
__device__ __forceinline__ float dpp_add_step(float x) {
    int ti = __builtin_amdgcn_update_dpp(0, __float_as_int(x), CTRL, ROW_MASK, 0xf, BC);
    return x + __int_as_float(ti);
}
__device__ __forceinline__ float wave_sum(float x) {
    x = dpp_add_step<0x111, 0xf, true >(x);  // row_shr:1 (0-fill)
    x = dpp_add_step<0x112, 0xf, true >(x);  // row_shr:2
    x = dpp_add_step<0x114, 0xf, true >(x);  // row_shr:4
    x = dpp_add_step<0x118, 0xf, true >(x);  // row_shr:8  -> lane15 of each row16 = row sum
    x = dpp_add_step<0x142, 0xa, false>(x);  // row_bcast15 into rows 1,3
    x = dpp_add_step<0x143, 0xc, false>(x);  // row_bcast31 into rows 2,3 -> lane63 = total
    return __int_as_float(__builtin_amdgcn_readlane(__float_as_int(x), 63));
}

__global__ void relayout_kernel(const float* __restrict__ img, unsigned int* __restrict__ tex) {
    int i = blockIdx.x*blockDim.x + threadIdx.x;
    const int HW = EH*EW;
    if (i < HW) {
        float r = img[i], g = img[HW + i], b = img[2*HW + i];
        float m = fmaxf(fmaxf(r, g), b);
        int es = min(max((int)(__float_as_uint(m) >> 23) - 111, 0), 31);
        float sc = __uint_as_float((unsigned int)(151 - es) << 23);   // 2^(24-es)
        unsigned int R = min(511u, (unsigned int)rintf(r*sc));
        unsigned int G = min(511u, (unsigned int)rintf(g*sc));
        unsigned int B = min(511u, (unsigned int)rintf(b*sc));
        tex[i] = ((unsigned int)es << 27) | (B << 18) | (G << 9) | R;
    }
}

template<bool TEX>
__global__ __launch_bounds__(256) void ibl_kernel(
    const float* __restrict__ emap, const unsigned int* __restrict__ tex,
    const float* __restrict__ view_dir, const float* __restrict__ normal,
    const float* __restrict__ albedo, const float* __restrict__ rough_,
    const float* __restrict__ metal_, const float* __restrict__ u1_,
    const float* __restrict__ u2_, const float* __restrict__ uc_,
    const float* __restrict__ vc_, float* __restrict__ out)
{
    int lane = threadIdx.x & 63;
    int wid  = (blockIdx.x << 2) + (threadIdx.x >> 6);   // wave id
    int p0   = __builtin_amdgcn_readfirstlane(wid << 1); // 2 points per wave, uniform

    // ---- streamed per-sample inputs (non-temporal; keep texture L2-resident) ----
    float U1[2], U2[2], UC[2], VC[2];
    F3 v[2], n[2], f0[2], kd[2];
    float alpha[2];
    #pragma unroll
    for (int k = 0; k < 2; ++k) {
        int p = p0 + k;
        size_t si = (size_t)p*SN + lane;
        U1[k] = __builtin_nontemporal_load(u1_ + si);
        U2[k] = __builtin_nontemporal_load(u2_ + si);
        UC[k] = __builtin_nontemporal_load(uc_ + si);
        VC[k] = __builtin_nontemporal_load(vc_ + si);
        v[k]   = F3{view_dir[3*p], view_dir[3*p+1], view_dir[3*p+2]};
        n[k]   = F3{normal[3*p],   normal[3*p+1],   normal[3*p+2]};
        F3 alb = F3{albedo[3*p],   albedo[3*p+1],   albedo[3*p+2]};
        float rg = rough_[p];
        alpha[k] = rg*rg;
        float metal = metal_[p];
        f0[k] = F3{metal*alb.x + (1.0f - metal)*0.04f,
                   metal*alb.y + (1.0f - metal)*0.04f,
                   metal*alb.z + (1.0f - metal)*0.04f};
        kd[k] = F3{alb.x*(1.0f - metal), alb.y*(1.0f - metal), alb.z*(1.0f - metal)};
    }

    // ---- per-point frames ----
    F3 t[2], b[2];
    #pragma unroll
    for (int k = 0; k < 2; ++k) {
        float nx2nz2 = n[k].x*n[k].x + n[k].z*n[k].z;
        if (nx2nz2 <= 0.0f) t[k] = F3{1.0f, 0.0f, 0.0f};
        else                t[k] = norm3(F3{n[k].z, 0.0f, -n[k].x});
        b[k] = cross3(n[k], t[k]);   // unit to ~1e-7
    }

    // ---- diffuse dirs: short chain, issue gathers FIRST ----
    uint2 dr0[2], dr1[2];
    float dwx[2], dwy[2];
    bool d_l[2], d_r[2];
    F3 ld[2];
    #pragma unroll
    for (int k = 0; k < 2; ++k) {
        float sph = __builtin_amdgcn_sinf(UC[k]);
        float cph = __builtin_amdgcn_cosf(UC[k]);
        float ct = __builtin_amdgcn_sqrtf(VC[k]);
        float st = __builtin_amdgcn_sqrtf(fmaxf(1.0f - VC[k], 0.0f));
        F3 ldl = F3{cph*st, sph*st, ct};
        ld[k] = F3{t[k].x*ldl.x + b[k].x*ldl.y + n[k].x*ldl.z,
                   t[k].y*ldl.x + b[k].y*ldl.y + n[k].y*ldl.z,
                   t[k].z*ldl.x + b[k].z*ldl.y + n[k].z*ldl.z};
        if (TEX) {
            int i0, i1;
            env_addr(ld[k], i0, i1, dwx[k], dwy[k], d_l[k], d_r[k]);
            dr0[k] = *reinterpret_cast<const uint2*>(tex + i0);
            dr1[k] = *reinterpret_cast<const uint2*>(tex + i1);
        }
    }

    // ---- spec chains (VALU hides diffuse-load latency) ----
    uint2 sr0[2], sr1[2];
    float swx[2], swy[2];
    bool s_l[2], s_r[2];
    F3 light[2];
    float sv_ratio[2];
    #pragma unroll
    for (int k = 0; k < 2; ++k) {
        F3 vl = F3{dot3(t[k], v[k]), dot3(b[k], v[k]), dot3(n[k], v[k])};
        float ndv = clampf(vl.z, 0.0f, 1.0f);
        float s_ndv = smithf(alpha[k], ndv);
        float inv_sv = __builtin_amdgcn_rcpf(clampf(s_ndv, 1e-10f, 1.0f));
        sv_ratio[k] = s_ndv * inv_sv;

        F3 vh = norm3(F3{vl.x*alpha[k], vl.y*alpha[k], vl.z});
        F3 b1;
        float l2d = vh.x*vh.x + vh.y*vh.y;
        if (l2d <= 0.0f) b1 = F3{1.0f, 0.0f, 0.0f};
        else             b1 = norm3(F3{-vh.y, vh.x, 0.0f});
        F3 b2 = cross3(vh, b1);
        float sfac = 0.5f*(1.0f + vh.z);

        float r = __builtin_amdgcn_sqrtf(U1[k]);
        float sth = __builtin_amdgcn_sinf(U2[k]);
        float cth = __builtin_amdgcn_cosf(U2[k]);
        float t1 = r*cth;
        float t2 = r*sth;
        t2 = (1.0f - sfac)*__builtin_amdgcn_sqrtf(fmaxf(1.0f - t1*t1, 0.0f)) + sfac*t2;
        float t3 = __builtin_amdgcn_sqrtf(clampf(1.0f - t1*t1 - t2*t2, 0.0f, 1.0f));
        F3 mh = F3{t1*b1.x + t2*b2.x + t3*vh.x,
                   t1*b1.y + t2*b2.y + t3*vh.y,
                   t1*b1.z + t2*b2.z + t3*vh.z};
        F3 ml = norm3(F3{mh.x*alpha[k], mh.y*alpha[k], mh.z});
        F3 m = F3{t[k].x*ml.x + b[k].x*ml.y + n[k].x*ml.z,
                  t[k].y*ml.x + b[k].y*ml.y + n[k].y*ml.z,
                  t[k].z*ml.x + b[k].z*ml.y + n[k].z*ml.z};
        float idm = dot3(v[k], m);
        light[k] = F3{fmaf(2.0f*idm, m.x, -v[k].x),
                      fmaf(2.0f*idm, m.y, -v[k].y),
                      fmaf(2.0f*idm, m.z, -v[k].z)};
        if (TEX) {
            int i0, i1;
            env_addr(light[k], i0, i1, swx[k], swy[k], s_l[k], s_r[k]);
            sr0[k] = *reinterpret_cast<const uint2*>(tex + i0);
            sr1[k] = *reinterpret_cast<const uint2*>(tex + i1);
        }
    }

    // ---- shading scalars (hide spec-load latency) ----
    float fresc[2];   // gs
    float om5[2];
    #pragma unroll
    for (int k = 0; k < 2; ++k) {
        F3 hlf = norm3(F3{v[k].x + light[k].x, v[k].y + light[k].y, v[k].z + light[k].z});
        float hdv = clampf(dot3(hlf, v[k]), 0.0f, 1.0f);
        float ndl = clampf(dot3(n[k], light[k]), 0.0f, 1.0f);
        float s_ndl = smithf(alpha[k], ndl);
        fresc[k] = sv_ratio[k] * s_ndl;
        float om = 1.0f - hdv;
        float om2 = om*om;
        om5[k] = om2*om2*om;
    }

    // ---- blends + DPP reduce + output ----
    #pragma unroll
    for (int k = 0; k < 2; ++k) {
        F3 rad, radd;
        if (TEX) {
            radd = env_blend9(dr0[k], dr1[k], dwx[k], dwy[k], d_l[k], d_r[k]);
            rad  = env_blend9(sr0[k], sr1[k], swx[k], swy[k], s_l[k], s_r[k]);
        } else {
            const int HW = EH*EW;
            #pragma unroll
            for (int pass = 0; pass < 2; ++pass) {
                F3 d = pass ? light[k] : ld[k];
                int i0, i1; float wx, wy; bool atl, atr;
                env_addr(d, i0, i1, wx, wy, atl, atr);
                int x0 = atr ? 1 : 0, x1 = atl ? 0 : 1;
                F3 o;
                float* po = &o.x;
                #pragma unroll
                for (int c = 0; c < 3; ++c) {
                    const float* pl = emap + c*HW;
                    float v00 = pl[i0 + x0], v01 = pl[i0 + x1];
                    float v10 = pl[i1 + x0], v11 = pl[i1 + x1];
                    float rr0 = fmaf(wx, v01 - v00, v00);
                    float rr1 = fmaf(wx, v11 - v10, v10);
                    po[c] = fmaf(wy, rr1 - rr0, rr0);
                }
                if (pass) rad = o; else radd = o;
            }
        }
        float gs = fresc[k];
        F3 acc;
        acc.x = fmaf((f0[k].x + (1.0f - f0[k].x)*om5[k])*gs, rad.x, radd.x*kd[k].x);
        acc.y = fmaf((f0[k].y + (1.0f - f0[k].y)*om5[k])*gs, rad.y, radd.y*kd[k].y);
        acc.z = fmaf((f0[k].z + (1.0f - f0[k].z)*om5[k])*gs, rad.z, radd.z*kd[k].z);

        float sx = wave_sum(acc.x);
        float sy = wave_sum(acc.y);
        float sz = wave_sum(acc.z);

        if (lane == 0) {
            const float inv_s = 1.0f/(float)SN;
            int p = p0 + k;
            __builtin_nontemporal_store(sx*inv_s, out + 3*p + 0);
            __builtin_nontemporal_store(sy*inv_s, out + 3*p + 1);
            __builtin_nontemporal_store(sz*inv_s, out + 3*p + 2);
        }
    }
}

} // anonymous namespace

extern "C" void kernel_launch(void* const* d_in, const int* in_sizes, int n_in,
                              void* d_out, int out_size, void* d_ws, size_t ws_size,
                              hipStream_t stream) {
    const float* emap     = (const float*)d_in[0];
    const float* view_dir = (const float*)d_in[1];
    const float* normal   = (const float*)d_in[2];
    const float* albedo   = (const float*)d_in[3];
    const float* rough    = (const float*)d_in[4];
    const float* metal    = (const float*)d_in[5];
    const float* u1       = (const float*)d_in[6];
    const float* u2       = (const float*)d_in[7];
    const float* uc       = (const float*)d_in[8];
    const float* vc       = (const float*)d_in[9];
    float* out            = (float*)d_out;

    const int HW = EH*EW;
    const size_t tex_bytes = (size_t)HW*sizeof(unsigned int);
    const int main_blocks = PN/8;   // 4 waves/block x 2 points/wave

    if (ws_size >= tex_bytes) {
        unsigned int* tex = (unsigned int*)d_ws;
        relayout_kernel<<<(HW + 255)/256, 256, 0, stream>>>(emap, tex);
        ibl_kernel<true><<<main_blocks, 256, 0, stream>>>(
            emap, tex, view_dir, normal, albedo, rough, metal, u1, u2, uc, vc, out);
    } else {
        ibl_kernel<false><<<main_blocks, 256, 0, stream>>>(
            emap, nullptr, view_dir, normal, albedo, rough, metal, u1, u2, uc, vc, out);
    }
}